// Round 12
// baseline (136.312 us; speedup 1.0000x reference)
//
#include <hip/hip_runtime.h>

typedef unsigned short u16;
typedef u16 u16x4 __attribute__((ext_vector_type(4)));
typedef u16 u16x8 __attribute__((ext_vector_type(8)));
typedef __bf16 bf16x8 __attribute__((ext_vector_type(8)));
typedef float f32x4 __attribute__((ext_vector_type(4)));

#define DEVINL static __device__ __forceinline__

DEVINL u16 f2bf(float f) {
    unsigned u = __builtin_bit_cast(unsigned, f);
    u += 0x7fff + ((u >> 16) & 1);           // RNE
    return (u16)(u >> 16);
}

DEVINL u16 pbf(float f) {                    // round-half-up, for P in [0, 2^8]
    unsigned u = __builtin_bit_cast(unsigned, f);
    return (u16)((u + 0x8000) >> 16);
}

DEVINL f32x4 mfma_bf16(u16x8 a, u16x8 b, f32x4 c) {
    return __builtin_amdgcn_mfma_f32_16x16x32_bf16(
        __builtin_bit_cast(bf16x8, a), __builtin_bit_cast(bf16x8, b), c, 0, 0, 0);
}

DEVINL void gload16(const void* g, void* lds) {
    __builtin_amdgcn_global_load_lds(
        (const __attribute__((address_space(1))) void*)g,
        (__attribute__((address_space(3))) void*)lds, 16, 0, 0);
}

// ---------------- conversion / transpose kernels ----------------

__global__ void cvt_x_kernel(const float4* __restrict__ x4, u16x4* __restrict__ o4) {
    int idx = blockIdx.x * 256 + threadIdx.x;
    float4 a = x4[idx];
    u16x4 o;
    o[0] = f2bf(a.x); o[1] = f2bf(a.y); o[2] = f2bf(a.z); o[3] = f2bf(a.w);
    o4[idx] = o;
}

__global__ void fill_bias(const float* __restrict__ bq, const float* __restrict__ bk,
                          const float* __restrict__ bv, float* __restrict__ dst) {
    int i = blockIdx.x * 256 + threadIdx.x;
    if (i < 1024) dst[i] = bq[i];
    else if (i < 1280) dst[i] = bk[i - 1024];
    else if (i < 1536) dst[i] = bv[i - 1280];
}

// src fp32 [1024][N] -> dst bf16 [(rowOff+n)][1024]
__global__ void twt_kernel(const float* __restrict__ src, u16* __restrict__ dst,
                           int N, int rowOff) {
    __shared__ float t[64][65];
    int k0 = blockIdx.x * 64, n0 = blockIdx.y * 64;
    int tid = threadIdx.x;
#pragma unroll
    for (int j = 0; j < 16; j++) {
        int idx = j * 256 + tid; int r = idx >> 6, c = idx & 63;
        t[r][c] = src[(size_t)(k0 + r) * N + n0 + c];
    }
    __syncthreads();
#pragma unroll
    for (int j = 0; j < 16; j++) {
        int idx = j * 256 + tid; int r = idx >> 6, c = idx & 63;
        dst[(size_t)(rowOff + n0 + r) * 1024 + k0 + c] = f2bf(t[c][r]);
    }
}

// qkv bf16 [8192][1536] V-section -> vt bf16 [(b*4+h)*64+hd][4096]
__global__ void tv_kernel(const u16* __restrict__ qkv, u16* __restrict__ vt) {
    __shared__ u16 t[64][68];
    int t0 = blockIdx.x * 64; int h = blockIdx.y; int b = blockIdx.z;
    int tid = threadIdx.x;
#pragma unroll
    for (int j = 0; j < 16; j++) {
        int idx = j * 256 + tid; int r = idx >> 6, c = idx & 63;
        t[r][c] = qkv[(size_t)(b * 4096 + t0 + r) * 1536 + 1280 + h * 64 + c];
    }
    __syncthreads();
#pragma unroll
    for (int j = 0; j < 16; j++) {
        int idx = j * 256 + tid; int r = idx >> 6, c = idx & 63;
        vt[(size_t)((b * 4 + h) * 64 + r) * 4096 + t0 + c] = t[c][r];
    }
}

// ---------------- 256x256 8-phase MFMA GEMM ----------------
// C[M][N] = (A[M][K] * Bt[N][K]^T + bias) * colscale. 512 thr = 8 waves (2Mx4N),
// per-wave C = 128x64 (8x4 frags). BK=64. LDS 128KB: [dbuf][A|B][half(128 rows)].
// Per K-tile T, 4 subphases: {ds_read A mf-pair (+B all at s=0) | stage 1 half-tile
// -> s_barrier -> lgkmcnt(0)+sched_barrier -> setprio(1) 16 MFMA setprio(0) -> s_barrier}.
// Stage: A(T+1) halves at s=0,1 (A slot free after T-1 done); B(T+2) at s=2,3
// (B consumed entirely at s=0 -> slot frees early). vmcnt(4) once per K-tile at s=3
// guarantees stages >=2 phases old have landed (derived; never vmcnt(0) in loop).
// Swizzle: byte ^= (row&7)<<4 via pre-swizzled global source + swizzled ds_read.

template <bool F32OUT>
__global__ __launch_bounds__(512, 2) void gemm256(
    const u16* __restrict__ A, const u16* __restrict__ Bt, void* __restrict__ Cp,
    const float* __restrict__ bias, int M, int N, int K, int qn, float qscale) {
    __shared__ __align__(16) u16 lds[2][2][2][8192];   // [dbuf][A=0/B=1][half][128*64]
    int tid = threadIdx.x, l = tid & 63, w = tid >> 6;
    int wr = w >> 2, wc = w & 3;

    int nwg = gridDim.x * gridDim.y;
    int lin = blockIdx.y * gridDim.x + blockIdx.x;
    int q_ = nwg >> 3, r_ = nwg & 7;
    int xcd = lin & 7, i_ = lin >> 3;
    int wgid = (xcd < r_ ? xcd * (q_ + 1) : r_ * (q_ + 1) + (xcd - r_) * q_) + i_;
    int m0 = (wgid / gridDim.x) * 256, n0 = (wgid % gridDim.x) * 256;

    f32x4 acc[8][4] = {};

    // staging addresses: 16 chunks of 1KB per 16KB half-tile; chunk = w*2+c
    int srow_[2], scol_[2];
#pragma unroll
    for (int c = 0; c < 2; c++) {
        int off = (w * 2 + c) * 1024 + l * 16;
        int row = off >> 7, inner = off & 127;
        srow_[c] = row;
        scol_[c] = (inner ^ ((row & 7) << 4)) >> 1;
    }

#define STG(dp, ab, h, base, kb)                                                    \
    do {                                                                            \
        _Pragma("unroll")                                                           \
        for (int c = 0; c < 2; c++)                                                 \
            gload16((base) + (size_t)((h) * 128 + srow_[c]) * K + (kb) + scol_[c],  \
                    (char*)&lds[dp][ab][h][0] + (w * 2 + c) * 1024);                \
    } while (0)

    const u16* Ab = A + (size_t)m0 * K;
    const u16* Bb = Bt + (size_t)n0 * K;
    int NKT = K >> 6, mask = NKT - 1;

    // prologue: A(0), B(0), B(1); full drain + barrier
    STG(0, 0, 0, Ab, 0); STG(0, 0, 1, Ab, 0);
    STG(0, 1, 0, Bb, 0); STG(0, 1, 1, Bb, 0);
    STG(1, 1, 0, Bb, 64); STG(1, 1, 1, Bb, 64);
    asm volatile("s_waitcnt vmcnt(0)" ::: "memory");
    __builtin_amdgcn_s_barrier();

    for (int T = 0; T < NKT; ++T) {
        int p = T & 1;
        int kbA = ((T + 1) & mask) << 6;     // A(T+1) -> dbuf (T+1)&1
        int kbB = ((T + 2) & mask) << 6;     // B(T+2) -> dbuf T&1
        u16x8 bfr[4][2];
#pragma unroll
        for (int s = 0; s < 4; ++s) {
            // ds_reads for this subphase
            u16x8 afr[2][2];
#pragma unroll
            for (int mi = 0; mi < 2; ++mi)
#pragma unroll
                for (int kc = 0; kc < 2; ++kc) {
                    int row = (2 * s + mi) * 16 + (l & 15);
                    int co = (kc * 32 + (l >> 4) * 8) * 2;
                    afr[mi][kc] = *(const u16x8*)((const char*)&lds[p][0][wr][0]
                                  + row * 128 + (co ^ ((row & 7) << 4)));
                }
            if (s == 0) {
#pragma unroll
                for (int nf = 0; nf < 4; ++nf)
#pragma unroll
                    for (int kc = 0; kc < 2; ++kc) {
                        int row = (wc & 1) * 64 + nf * 16 + (l & 15);
                        int co = (kc * 32 + (l >> 4) * 8) * 2;
                        bfr[nf][kc] = *(const u16x8*)((const char*)&lds[p][1][wc >> 1][0]
                                      + row * 128 + (co ^ ((row & 7) << 4)));
                    }
            }
            // stage one half-tile
            if (s == 0)      STG(p ^ 1, 0, 0, Ab, kbA);
            else if (s == 1) STG(p ^ 1, 0, 1, Ab, kbA);
            else if (s == 2) STG(p, 1, 0, Bb, kbB);
            else {
                STG(p, 1, 1, Bb, kbB);
                asm volatile("s_waitcnt vmcnt(4)" ::: "memory");
            }
            __builtin_amdgcn_s_barrier();
            asm volatile("s_waitcnt lgkmcnt(0)" ::: "memory");
            __builtin_amdgcn_sched_barrier(0);
            __builtin_amdgcn_s_setprio(1);
#pragma unroll
            for (int kc = 0; kc < 2; ++kc)
#pragma unroll
                for (int mi = 0; mi < 2; ++mi)
#pragma unroll
                    for (int nf = 0; nf < 4; ++nf)
                        acc[2 * s + mi][nf] =
                            mfma_bf16(afr[mi][kc], bfr[nf][kc], acc[2 * s + mi][nf]);
            __builtin_amdgcn_s_setprio(0);
            __builtin_amdgcn_s_barrier();
        }
    }
#undef STG
    asm volatile("s_waitcnt vmcnt(0)" ::: "memory");   // dangling wrapped prefetches

#pragma unroll
    for (int mf = 0; mf < 8; ++mf) {
#pragma unroll
        for (int nf = 0; nf < 4; ++nf) {
            int col = n0 + wc * 64 + nf * 16 + (l & 15);
            float bv = bias ? bias[col] : 0.0f;
            float scl = (col < qn) ? qscale : 1.0f;
#pragma unroll
            for (int r = 0; r < 4; r++) {
                int row = m0 + wr * 128 + mf * 16 + (l >> 4) * 4 + r;
                float v = (acc[mf][nf][r] + bv) * scl;
                if (F32OUT) ((float*)Cp)[(size_t)row * N + col] = v;
                else        ((u16*)Cp)[(size_t)row * N + col] = f2bf(v);
            }
        }
    }
}

// ---------------- banded GQA flash attention (R8 structure, measured 41.7us) ----------------
// block = (qblock 64, head-pair, b); grid 64x8x2 = 1024 blocks = 4/CU.
// 8 waves = 2 q-heads x 4 q-fragments (16 rows each). LDS 32KB, VGPR 48.
// Frozen: 5 perturbations (R4/R6/R7/R9/R11) all regressed.

__global__ __launch_bounds__(512, 4) void attn_kernel(
    const u16* __restrict__ qkv, const u16* __restrict__ vt, u16* __restrict__ y) {
    __shared__ __align__(16) u16 Ks[64 * 64];
    __shared__ __align__(16) u16 Vs[64 * 64];
    __shared__ __align__(16) u16 Ps[8][16 * 64];
    int tid = threadIdx.x, l = tid & 63, w = tid >> 6;
    int qb = ((blockIdx.x & 7) << 3) | (blockIdx.x >> 3);
    int h = blockIdx.y >> 1, hp = blockIdx.y & 1, b = blockIdx.z;
    int qstart = qb * 64;
    size_t rowbase = (size_t)b * 4096;
    int hq = h * 4 + hp * 2 + (w >> 2);
    int qrow0 = (w & 3) * 16;

    u16x8 qf_[2];
#pragma unroll
    for (int kc = 0; kc < 2; ++kc)
        qf_[kc] = *(const u16x8*)(qkv + (rowbase + qstart + qrow0 + (l & 15)) * 1536
                                  + hq * 64 + kc * 32 + (l >> 4) * 8);

    f32x4 o[4] = {};
    float mrow = -__builtin_inff(), srow_ = 0.f;

    const u16* kbase_ptr = qkv + 1024 + h * 64;
    const u16* vbase_ptr = vt + (size_t)((b * 4 + h) * 64) * 4096;

    int sb_ = w * 1024 + l * 16;
    int g_row = sb_ >> 7, g_inner = sb_ & 127;
    int g_col = (g_inner ^ ((g_row & 7) << 4)) >> 1;

#pragma unroll
    for (int kstart = qstart - 256; kstart <= qstart + 256; kstart += 64) {
        if (kstart < 0 || kstart >= 4096) continue;
        gload16(kbase_ptr + (rowbase + kstart + g_row) * 1536 + g_col, (char*)Ks + w * 1024);
        gload16(vbase_ptr + (size_t)g_row * 4096 + kstart + g_col, (char*)Vs + w * 1024);
        __syncthreads();

        f32x4 st[4] = {};
#pragma unroll
        for (int kc = 0; kc < 2; ++kc) {
            int co = (kc * 32 + (l >> 4) * 8) * 2;
#pragma unroll
            for (int kf = 0; kf < 4; ++kf) {
                int row = kf * 16 + (l & 15);
                u16x8 kfr = *(const u16x8*)((const char*)Ks + row * 128 + (co ^ ((row & 7) << 4)));
                st[kf] = mfma_bf16(kfr, qf_[kc], st[kf]);
            }
        }

        bool mlo = (kstart == qstart - 256);
        bool mhi = (kstart == qstart + 256);

        int qoff = qrow0 + (l & 15);
        float pmax = -1e30f;
        float sv[4][4];
#pragma unroll
        for (int kf = 0; kf < 4; ++kf)
#pragma unroll
            for (int r = 0; r < 4; r++) {
                int koff = kf * 16 + (l >> 4) * 4 + r;
                float v = st[kf][r];
                if (mlo && koff < qoff) v = -1e30f;
                if (mhi && koff > qoff) v = -1e30f;
                sv[kf][r] = v;
                pmax = fmaxf(pmax, v);
            }
        pmax = fmaxf(pmax, __shfl_xor(pmax, 16));
        pmax = fmaxf(pmax, __shfl_xor(pmax, 32));

        bool resc = !__all(pmax - mrow <= 8.0f);
        float newm = resc ? fmaxf(mrow, pmax) : mrow;
        float psum = 0.f;
#pragma unroll
        for (int kf = 0; kf < 4; ++kf) {
            u16x4 pk;
#pragma unroll
            for (int r = 0; r < 4; r++) {
                float e = __builtin_amdgcn_exp2f(sv[kf][r] - newm);
                psum += e;
                pk[r] = pbf(e);
            }
            int row = l & 15;
            int keyc = kf * 16 + (l >> 4) * 4;
            *(u16x4*)((char*)Ps[w] + ((row * 128 + keyc * 2) ^ ((row & 7) << 4))) = pk;
        }
        psum += __shfl_xor(psum, 16);
        psum += __shfl_xor(psum, 32);
        if (resc) {
            float fs = __builtin_amdgcn_exp2f(mrow - newm);
            srow_ = srow_ * fs + psum;
            mrow = newm;
#pragma unroll
            for (int r = 0; r < 4; r++) {
                float fb = __shfl(fs, (l >> 4) * 4 + r);
#pragma unroll
                for (int nf = 0; nf < 4; ++nf) o[nf][r] *= fb;
            }
        } else {
            srow_ += psum;
        }

#pragma unroll
        for (int kc = 0; kc < 2; ++kc) {
            int co = (kc * 32 + (l >> 4) * 8) * 2;
            int prow = l & 15;
            u16x8 pa = *(const u16x8*)((const char*)Ps[w] + ((prow * 128 + co) ^ ((prow & 7) << 4)));
#pragma unroll
            for (int nf = 0; nf < 4; ++nf) {
                int row = nf * 16 + (l & 15);
                u16x8 vb = *(const u16x8*)((const char*)Vs + row * 128 + (co ^ ((row & 7) << 4)));
                o[nf] = mfma_bf16(pa, vb, o[nf]);
            }
        }
        __syncthreads();
    }

    float inv = 1.0f / srow_;
#pragma unroll
    for (int r = 0; r < 4; r++) {
        float sb = __shfl(inv, (l >> 4) * 4 + r);
        int row = qstart + qrow0 + (l >> 4) * 4 + r;
#pragma unroll
        for (int nf = 0; nf < 4; ++nf) {
            int col = hq * 64 + nf * 16 + (l & 15);
            y[(rowbase + row) * 1024 + col] = f2bf(o[nf][r] * sb);
        }
    }
}

// ---------------- host launch ----------------

extern "C" void kernel_launch(void* const* d_in, const int* in_sizes, int n_in,
                              void* d_out, int out_size, void* d_ws, size_t ws_size,
                              hipStream_t stream) {
    const float* x  = (const float*)d_in[0];
    const float* wq = (const float*)d_in[1];
    const float* bq = (const float*)d_in[2];
    const float* wk = (const float*)d_in[3];
    const float* bk = (const float*)d_in[4];
    const float* wv = (const float*)d_in[5];
    const float* bv = (const float*)d_in[6];
    const float* wo = (const float*)d_in[7];
    const float* bo = (const float*)d_in[8];
    float* out = (float*)d_out;

    char* p = (char*)d_ws;
    u16* xb     = (u16*)p;   p += (size_t)8192 * 1024 * 2;   // x bf16
    u16* wqkvt  = (u16*)p;   p += (size_t)1536 * 1024 * 2;   // [n][k] bf16 (q,k,v concat)
    u16* wot    = (u16*)p;   p += (size_t)1024 * 1024 * 2;   // wo^T bf16
    float* bqkv = (float*)p; p += 8192;                      // 1536 fp32 (padded)
    u16* qkvb   = (u16*)p;   p += (size_t)8192 * 1536 * 2;   // QKV bf16
    u16* vtb    = (u16*)p;   p += (size_t)512 * 4096 * 2;    // V^T bf16
    u16* yb     = (u16*)p;                                   // attn out bf16

    cvt_x_kernel<<<8192, 256, 0, stream>>>((const float4*)x, (u16x4*)xb);
    fill_bias<<<6, 256, 0, stream>>>(bq, bk, bv, bqkv);
    twt_kernel<<<dim3(16, 16), 256, 0, stream>>>(wq, wqkvt, 1024, 0);
    twt_kernel<<<dim3(16, 4),  256, 0, stream>>>(wk, wqkvt, 256, 1024);
    twt_kernel<<<dim3(16, 4),  256, 0, stream>>>(wv, wqkvt, 256, 1280);
    twt_kernel<<<dim3(16, 16), 256, 0, stream>>>(wo, wot, 1024, 0);

    // Q columns pre-scaled by 0.125*log2(e) so attention scores are in log2 domain
    gemm256<false><<<dim3(6, 32), 512, 0, stream>>>(xb, wqkvt, qkvb, bqkv,
                                                    8192, 1536, 1024, 1024, 0.18033688f);
    tv_kernel<<<dim3(64, 4, 2), 256, 0, stream>>>(qkvb, vtb);
    attn_kernel<<<dim3(64, 8, 2), 512, 0, stream>>>(qkvb, vtb, yb);
    gemm256<true><<<dim3(4, 32), 512, 0, stream>>>(yb, wot, out, bo,
                                                   8192, 1024, 1024, 0, 1.0f);
}

// Round 13
// 109.244 us; speedup vs baseline: 1.2478x; 1.2478x over previous
//
#include <hip/hip_runtime.h>

typedef unsigned short u16;
typedef u16 u16x4 __attribute__((ext_vector_type(4)));
typedef u16 u16x8 __attribute__((ext_vector_type(8)));
typedef __bf16 bf16x8 __attribute__((ext_vector_type(8)));
typedef float f32x4 __attribute__((ext_vector_type(4)));

#define DEVINL static __device__ __forceinline__

DEVINL u16 f2bf(float f) {
    unsigned u = __builtin_bit_cast(unsigned, f);
    u += 0x7fff + ((u >> 16) & 1);           // RNE
    return (u16)(u >> 16);
}

DEVINL u16 pbf(float f) {                    // round-half-up, for P in [0, 2^8]
    unsigned u = __builtin_bit_cast(unsigned, f);
    return (u16)((u + 0x8000) >> 16);
}

DEVINL f32x4 mfma_bf16(u16x8 a, u16x8 b, f32x4 c) {
    return __builtin_amdgcn_mfma_f32_16x16x32_bf16(
        __builtin_bit_cast(bf16x8, a), __builtin_bit_cast(bf16x8, b), c, 0, 0, 0);
}

DEVINL void gload16(const void* g, void* lds) {
    __builtin_amdgcn_global_load_lds(
        (const __attribute__((address_space(1))) void*)g,
        (__attribute__((address_space(3))) void*)lds, 16, 0, 0);
}

// ---------------- unified preprocessing kernel ----------------
// Sections by blockIdx.x:
//  [0, 8192)        : x fp32 -> bf16 (float4/thread)
//  [8192, 8448)     : transpose+cvt wq -> wqkvt rows [0,1024)
//  [8448, 8512)     : transpose+cvt wk -> wqkvt rows [1024,1280)
//  [8512, 8576)     : transpose+cvt wv -> wqkvt rows [1280,1536)
//  [8576, 8832)     : transpose+cvt wo -> wot
//  [8832, 8838)     : pack biases

DEVINL void twt_body(const float* __restrict__ src, u16* __restrict__ dst,
                     int N, int rowOff, int bx, int by, int tid, float (*t)[65]) {
    int k0 = bx * 64, n0 = by * 64;
#pragma unroll
    for (int j = 0; j < 16; j++) {
        int idx = j * 256 + tid; int r = idx >> 6, c = idx & 63;
        t[r][c] = src[(size_t)(k0 + r) * N + n0 + c];
    }
    __syncthreads();
#pragma unroll
    for (int j = 0; j < 16; j++) {
        int idx = j * 256 + tid; int r = idx >> 6, c = idx & 63;
        dst[(size_t)(rowOff + n0 + r) * 1024 + k0 + c] = f2bf(t[c][r]);
    }
}

__global__ void prep_kernel(const float* __restrict__ x,
                            const float* __restrict__ wq, const float* __restrict__ bq,
                            const float* __restrict__ wk, const float* __restrict__ bk,
                            const float* __restrict__ wv, const float* __restrict__ bv,
                            const float* __restrict__ wo,
                            u16* __restrict__ xb, u16* __restrict__ wqkvt,
                            u16* __restrict__ wot, float* __restrict__ bqkv) {
    __shared__ float t[64][65];
    int bid = blockIdx.x, tid = threadIdx.x;
    if (bid < 8192) {
        int idx = bid * 256 + tid;
        float4 a = ((const float4*)x)[idx];
        u16x4 o;
        o[0] = f2bf(a.x); o[1] = f2bf(a.y); o[2] = f2bf(a.z); o[3] = f2bf(a.w);
        ((u16x4*)xb)[idx] = o;
    } else if (bid < 8448) {
        int id = bid - 8192; twt_body(wq, wqkvt, 1024, 0, id & 15, id >> 4, tid, t);
    } else if (bid < 8512) {
        int id = bid - 8448; twt_body(wk, wqkvt, 256, 1024, id & 15, id >> 4, tid, t);
    } else if (bid < 8576) {
        int id = bid - 8512; twt_body(wv, wqkvt, 256, 1280, id & 15, id >> 4, tid, t);
    } else if (bid < 8832) {
        int id = bid - 8576; twt_body(wo, wot, 1024, 0, id & 15, id >> 4, tid, t);
    } else {
        int i = (bid - 8832) * 256 + tid;
        if (i < 1024) bqkv[i] = bq[i];
        else if (i < 1280) bqkv[i] = bk[i - 1024];
        else if (i < 1536) bqkv[i] = bv[i - 1280];
    }
}

// qkv bf16 [8192][1536] V-section -> vt bf16 [(b*4+h)*64+hd][4096]
__global__ void tv_kernel(const u16* __restrict__ qkv, u16* __restrict__ vt) {
    __shared__ u16 t[64][68];
    int t0 = blockIdx.x * 64; int h = blockIdx.y; int b = blockIdx.z;
    int tid = threadIdx.x;
#pragma unroll
    for (int j = 0; j < 16; j++) {
        int idx = j * 256 + tid; int r = idx >> 6, c = idx & 63;
        t[r][c] = qkv[(size_t)(b * 4096 + t0 + r) * 1536 + 1280 + h * 64 + c];
    }
    __syncthreads();
#pragma unroll
    for (int j = 0; j < 16; j++) {
        int idx = j * 256 + tid; int r = idx >> 6, c = idx & 63;
        vt[(size_t)((b * 4 + h) * 64 + r) * 4096 + t0 + c] = t[c][r];
    }
}

// ---------------- MFMA GEMM: C[M][N] = (A[M][K] * Bt[N][K]^T + bias) * colscale ----------------
// R10 structure (proven best). Bijective chunked XCD swizzle (m204).

template <bool F32OUT>
__global__ __launch_bounds__(256, 2) void gemm_bt(
    const u16* __restrict__ A, const u16* __restrict__ Bt, void* __restrict__ Cp,
    const float* __restrict__ bias, int M, int N, int K, int qn, float qscale) {
    __shared__ __align__(16) u16 As[128 * 64];
    __shared__ __align__(16) u16 Bs[128 * 64];
    int tid = threadIdx.x; int l = tid & 63; int w = tid >> 6;

    int nwg = gridDim.x * gridDim.y;
    int lin = blockIdx.y * gridDim.x + blockIdx.x;
    int q_ = nwg >> 3, r_ = nwg & 7;
    int xcd = lin & 7, i_ = lin >> 3;
    int wgid = (xcd < r_ ? xcd * (q_ + 1) : r_ * (q_ + 1) + (xcd - r_) * q_) + i_;
    int m0 = (wgid / gridDim.x) * 128, n0 = (wgid % gridDim.x) * 128;

    int wm = (w >> 1) * 64, wn = (w & 1) * 64;
    f32x4 acc[4][4] = {};

    int srow[4], scol[4];
#pragma unroll
    for (int c = 0; c < 4; c++) {
        int b = (w * 4 + c) * 1024 + l * 16;
        int row = b >> 7, inner = b & 127;
        srow[c] = row;
        scol[c] = (inner ^ ((row & 7) << 4)) >> 1;
    }
    int nk = K >> 6;
    for (int kt = 0; kt < nk; ++kt) {
        int kb = kt << 6;
#pragma unroll
        for (int c = 0; c < 4; c++) {
            gload16(A + (size_t)(m0 + srow[c]) * K + kb + scol[c], (char*)As + (w * 4 + c) * 1024);
            gload16(Bt + (size_t)(n0 + srow[c]) * K + kb + scol[c], (char*)Bs + (w * 4 + c) * 1024);
        }
        __syncthreads();
#pragma unroll
        for (int kc = 0; kc < 2; ++kc) {
            int co = (kc * 32 + (l >> 4) * 8) * 2;
            u16x8 af[4], bf[4];
#pragma unroll
            for (int mf = 0; mf < 4; ++mf) {
                int row = wm + mf * 16 + (l & 15);
                af[mf] = *(const u16x8*)((const char*)As + row * 128 + (co ^ ((row & 7) << 4)));
            }
#pragma unroll
            for (int nf = 0; nf < 4; ++nf) {
                int row = wn + nf * 16 + (l & 15);
                bf[nf] = *(const u16x8*)((const char*)Bs + row * 128 + (co ^ ((row & 7) << 4)));
            }
#pragma unroll
            for (int mf = 0; mf < 4; ++mf)
#pragma unroll
                for (int nf = 0; nf < 4; ++nf)
                    acc[mf][nf] = mfma_bf16(af[mf], bf[nf], acc[mf][nf]);
        }
        __syncthreads();
    }
#pragma unroll
    for (int mf = 0; mf < 4; ++mf) {
#pragma unroll
        for (int nf = 0; nf < 4; ++nf) {
            int col = n0 + wn + nf * 16 + (l & 15);
            float bv = bias ? bias[col] : 0.0f;
            float scl = (col < qn) ? qscale : 1.0f;   // uniform per 16-lane group
#pragma unroll
            for (int r = 0; r < 4; r++) {
                int row = m0 + wm + mf * 16 + (l >> 4) * 4 + r;
                float v = (acc[mf][nf][r] + bv) * scl;
                if (F32OUT) ((float*)Cp)[(size_t)row * N + col] = v;
                else        ((u16*)Cp)[(size_t)row * N + col] = f2bf(v);
            }
        }
    }
}

// ---------------- banded GQA flash attention (R8 structure, measured 41.7us) ----------------
// Frozen: 5 perturbations (R4/R6/R7/R9/R11) all regressed.

__global__ __launch_bounds__(512, 4) void attn_kernel(
    const u16* __restrict__ qkv, const u16* __restrict__ vt, u16* __restrict__ y) {
    __shared__ __align__(16) u16 Ks[64 * 64];
    __shared__ __align__(16) u16 Vs[64 * 64];
    __shared__ __align__(16) u16 Ps[8][16 * 64];
    int tid = threadIdx.x, l = tid & 63, w = tid >> 6;
    int qb = ((blockIdx.x & 7) << 3) | (blockIdx.x >> 3);
    int h = blockIdx.y >> 1, hp = blockIdx.y & 1, b = blockIdx.z;
    int qstart = qb * 64;
    size_t rowbase = (size_t)b * 4096;
    int hq = h * 4 + hp * 2 + (w >> 2);
    int qrow0 = (w & 3) * 16;

    u16x8 qf_[2];
#pragma unroll
    for (int kc = 0; kc < 2; ++kc)
        qf_[kc] = *(const u16x8*)(qkv + (rowbase + qstart + qrow0 + (l & 15)) * 1536
                                  + hq * 64 + kc * 32 + (l >> 4) * 8);

    f32x4 o[4] = {};
    float mrow = -__builtin_inff(), srow_ = 0.f;

    const u16* kbase_ptr = qkv + 1024 + h * 64;
    const u16* vbase_ptr = vt + (size_t)((b * 4 + h) * 64) * 4096;

    int sb_ = w * 1024 + l * 16;
    int g_row = sb_ >> 7, g_inner = sb_ & 127;
    int g_col = (g_inner ^ ((g_row & 7) << 4)) >> 1;

#pragma unroll
    for (int kstart = qstart - 256; kstart <= qstart + 256; kstart += 64) {
        if (kstart < 0 || kstart >= 4096) continue;
        gload16(kbase_ptr + (rowbase + kstart + g_row) * 1536 + g_col, (char*)Ks + w * 1024);
        gload16(vbase_ptr + (size_t)g_row * 4096 + kstart + g_col, (char*)Vs + w * 1024);
        __syncthreads();

        f32x4 st[4] = {};
#pragma unroll
        for (int kc = 0; kc < 2; ++kc) {
            int co = (kc * 32 + (l >> 4) * 8) * 2;
#pragma unroll
            for (int kf = 0; kf < 4; ++kf) {
                int row = kf * 16 + (l & 15);
                u16x8 kfr = *(const u16x8*)((const char*)Ks + row * 128 + (co ^ ((row & 7) << 4)));
                st[kf] = mfma_bf16(kfr, qf_[kc], st[kf]);
            }
        }

        bool mlo = (kstart == qstart - 256);
        bool mhi = (kstart == qstart + 256);

        int qoff = qrow0 + (l & 15);
        float pmax = -1e30f;
        float sv[4][4];
#pragma unroll
        for (int kf = 0; kf < 4; ++kf)
#pragma unroll
            for (int r = 0; r < 4; r++) {
                int koff = kf * 16 + (l >> 4) * 4 + r;
                float v = st[kf][r];
                if (mlo && koff < qoff) v = -1e30f;
                if (mhi && koff > qoff) v = -1e30f;
                sv[kf][r] = v;
                pmax = fmaxf(pmax, v);
            }
        pmax = fmaxf(pmax, __shfl_xor(pmax, 16));
        pmax = fmaxf(pmax, __shfl_xor(pmax, 32));

        bool resc = !__all(pmax - mrow <= 8.0f);
        float newm = resc ? fmaxf(mrow, pmax) : mrow;
        float psum = 0.f;
#pragma unroll
        for (int kf = 0; kf < 4; ++kf) {
            u16x4 pk;
#pragma unroll
            for (int r = 0; r < 4; r++) {
                float e = __builtin_amdgcn_exp2f(sv[kf][r] - newm);
                psum += e;
                pk[r] = pbf(e);
            }
            int row = l & 15;
            int keyc = kf * 16 + (l >> 4) * 4;
            *(u16x4*)((char*)Ps[w] + ((row * 128 + keyc * 2) ^ ((row & 7) << 4))) = pk;
        }
        psum += __shfl_xor(psum, 16);
        psum += __shfl_xor(psum, 32);
        if (resc) {
            float fs = __builtin_amdgcn_exp2f(mrow - newm);
            srow_ = srow_ * fs + psum;
            mrow = newm;
#pragma unroll
            for (int r = 0; r < 4; r++) {
                float fb = __shfl(fs, (l >> 4) * 4 + r);
#pragma unroll
                for (int nf = 0; nf < 4; ++nf) o[nf][r] *= fb;
            }
        } else {
            srow_ += psum;
        }

#pragma unroll
        for (int kc = 0; kc < 2; ++kc) {
            int co = (kc * 32 + (l >> 4) * 8) * 2;
            int prow = l & 15;
            u16x8 pa = *(const u16x8*)((const char*)Ps[w] + ((prow * 128 + co) ^ ((prow & 7) << 4)));
#pragma unroll
            for (int nf = 0; nf < 4; ++nf) {
                int row = nf * 16 + (l & 15);
                u16x8 vb = *(const u16x8*)((const char*)Vs + row * 128 + (co ^ ((row & 7) << 4)));
                o[nf] = mfma_bf16(pa, vb, o[nf]);
            }
        }
        __syncthreads();
    }

    float inv = 1.0f / srow_;
#pragma unroll
    for (int r = 0; r < 4; r++) {
        float sb = __shfl(inv, (l >> 4) * 4 + r);
        int row = qstart + qrow0 + (l >> 4) * 4 + r;
#pragma unroll
        for (int nf = 0; nf < 4; ++nf) {
            int col = hq * 64 + nf * 16 + (l & 15);
            y[(rowbase + row) * 1024 + col] = f2bf(o[nf][r] * sb);
        }
    }
}

// ---------------- host launch ----------------

extern "C" void kernel_launch(void* const* d_in, const int* in_sizes, int n_in,
                              void* d_out, int out_size, void* d_ws, size_t ws_size,
                              hipStream_t stream) {
    const float* x  = (const float*)d_in[0];
    const float* wq = (const float*)d_in[1];
    const float* bq = (const float*)d_in[2];
    const float* wk = (const float*)d_in[3];
    const float* bk = (const float*)d_in[4];
    const float* wv = (const float*)d_in[5];
    const float* bv = (const float*)d_in[6];
    const float* wo = (const float*)d_in[7];
    const float* bo = (const float*)d_in[8];
    float* out = (float*)d_out;

    char* p = (char*)d_ws;
    u16* xb     = (u16*)p;   p += (size_t)8192 * 1024 * 2;   // x bf16
    u16* wqkvt  = (u16*)p;   p += (size_t)1536 * 1024 * 2;   // [n][k] bf16 (q,k,v concat)
    u16* wot    = (u16*)p;   p += (size_t)1024 * 1024 * 2;   // wo^T bf16
    float* bqkv = (float*)p; p += 8192;                      // 1536 fp32 (padded)
    u16* qkvb   = (u16*)p;   p += (size_t)8192 * 1536 * 2;   // QKV bf16
    u16* vtb    = (u16*)p;   p += (size_t)512 * 4096 * 2;    // V^T bf16
    u16* yb     = (u16*)p;                                   // attn out bf16

    prep_kernel<<<8838, 256, 0, stream>>>(x, wq, bq, wk, bk, wv, bv, wo,
                                          xb, wqkvt, wot, bqkv);

    // Q columns pre-scaled by 0.125*log2(e) so attention scores are in log2 domain
    gemm_bt<false><<<dim3(12, 64), 256, 0, stream>>>(xb, wqkvt, qkvb, bqkv,
                                                     8192, 1536, 1024, 1024, 0.18033688f);
    tv_kernel<<<dim3(64, 4, 2), 256, 0, stream>>>(qkvb, vtb);
    attn_kernel<<<dim3(64, 8, 2), 512, 0, stream>>>(qkvb, vtb, yb);
    gemm_bt<true><<<dim3(8, 64), 256, 0, stream>>>(yb, wot, out, bo,
                                                   8192, 1024, 1024, 0, 1.0f);
}

// Round 14
// 107.328 us; speedup vs baseline: 1.2701x; 1.0179x over previous
//
#include <hip/hip_runtime.h>

typedef unsigned short u16;
typedef u16 u16x4 __attribute__((ext_vector_type(4)));
typedef u16 u16x8 __attribute__((ext_vector_type(8)));
typedef __bf16 bf16x8 __attribute__((ext_vector_type(8)));
typedef float f32x4 __attribute__((ext_vector_type(4)));

#define DEVINL static __device__ __forceinline__

DEVINL u16 f2bf(float f) {
    unsigned u = __builtin_bit_cast(unsigned, f);
    u += 0x7fff + ((u >> 16) & 1);           // RNE
    return (u16)(u >> 16);
}

DEVINL u16 pbf(float f) {                    // round-half-up, for P in [0, 2^8]
    unsigned u = __builtin_bit_cast(unsigned, f);
    return (u16)((u + 0x8000) >> 16);
}

DEVINL f32x4 mfma_bf16(u16x8 a, u16x8 b, f32x4 c) {
    return __builtin_amdgcn_mfma_f32_16x16x32_bf16(
        __builtin_bit_cast(bf16x8, a), __builtin_bit_cast(bf16x8, b), c, 0, 0, 0);
}

DEVINL void gload16(const void* g, void* lds) {
    __builtin_amdgcn_global_load_lds(
        (const __attribute__((address_space(1))) void*)g,
        (__attribute__((address_space(3))) void*)lds, 16, 0, 0);
}

// ---------------- unified preprocessing kernel ----------------
// Sections by blockIdx.x:
//  [0, 8192)        : x fp32 -> bf16 (float4/thread)
//  [8192, 8448)     : transpose+cvt wq -> wqkvt rows [0,1024)
//  [8448, 8512)     : transpose+cvt wk -> wqkvt rows [1024,1280)
//  [8512, 8576)     : transpose+cvt wv -> wqkvt rows [1280,1536)
//  [8576, 8832)     : transpose+cvt wo -> wot
//  [8832, 8838)     : pack biases

DEVINL void twt_body(const float* __restrict__ src, u16* __restrict__ dst,
                     int N, int rowOff, int bx, int by, int tid, float (*t)[65]) {
    int k0 = bx * 64, n0 = by * 64;
#pragma unroll
    for (int j = 0; j < 16; j++) {
        int idx = j * 256 + tid; int r = idx >> 6, c = idx & 63;
        t[r][c] = src[(size_t)(k0 + r) * N + n0 + c];
    }
    __syncthreads();
#pragma unroll
    for (int j = 0; j < 16; j++) {
        int idx = j * 256 + tid; int r = idx >> 6, c = idx & 63;
        dst[(size_t)(rowOff + n0 + r) * 1024 + k0 + c] = f2bf(t[c][r]);
    }
}

__global__ void prep_kernel(const float* __restrict__ x,
                            const float* __restrict__ wq, const float* __restrict__ bq,
                            const float* __restrict__ wk, const float* __restrict__ bk,
                            const float* __restrict__ wv, const float* __restrict__ bv,
                            const float* __restrict__ wo,
                            u16* __restrict__ xb, u16* __restrict__ wqkvt,
                            u16* __restrict__ wot, float* __restrict__ bqkv) {
    __shared__ float t[64][65];
    int bid = blockIdx.x, tid = threadIdx.x;
    if (bid < 8192) {
        int idx = bid * 256 + tid;
        float4 a = ((const float4*)x)[idx];
        u16x4 o;
        o[0] = f2bf(a.x); o[1] = f2bf(a.y); o[2] = f2bf(a.z); o[3] = f2bf(a.w);
        ((u16x4*)xb)[idx] = o;
    } else if (bid < 8448) {
        int id = bid - 8192; twt_body(wq, wqkvt, 1024, 0, id & 15, id >> 4, tid, t);
    } else if (bid < 8512) {
        int id = bid - 8448; twt_body(wk, wqkvt, 256, 1024, id & 15, id >> 4, tid, t);
    } else if (bid < 8576) {
        int id = bid - 8512; twt_body(wv, wqkvt, 256, 1280, id & 15, id >> 4, tid, t);
    } else if (bid < 8832) {
        int id = bid - 8576; twt_body(wo, wot, 1024, 0, id & 15, id >> 4, tid, t);
    } else {
        int i = (bid - 8832) * 256 + tid;
        if (i < 1024) bqkv[i] = bq[i];
        else if (i < 1280) bqkv[i] = bk[i - 1024];
        else if (i < 1536) bqkv[i] = bv[i - 1280];
    }
}

// ---------------- MFMA GEMM: C[M][N] = (A[M][K] * Bt[N][K]^T + bias) * colscale ----------------
// R10 structure (proven best). Bijective chunked XCD swizzle (m204).
// VSPLIT: cols >= 1280 (V-section; whole n-tiles) are written DIRECTLY TRANSPOSED
// into vt[(b*256 + col-1280)*4096 + t] as u16x4 (4 consecutive t), replacing the
// separate tv_kernel pass; the qkvb V-write is skipped (nothing reads it).

template <bool F32OUT, bool VSPLIT>
__global__ __launch_bounds__(256, 2) void gemm_bt(
    const u16* __restrict__ A, const u16* __restrict__ Bt, void* __restrict__ Cp,
    const float* __restrict__ bias, u16* __restrict__ vt,
    int M, int N, int K, int qn, float qscale) {
    __shared__ __align__(16) u16 As[128 * 64];
    __shared__ __align__(16) u16 Bs[128 * 64];
    int tid = threadIdx.x; int l = tid & 63; int w = tid >> 6;

    int nwg = gridDim.x * gridDim.y;
    int lin = blockIdx.y * gridDim.x + blockIdx.x;
    int q_ = nwg >> 3, r_ = nwg & 7;
    int xcd = lin & 7, i_ = lin >> 3;
    int wgid = (xcd < r_ ? xcd * (q_ + 1) : r_ * (q_ + 1) + (xcd - r_) * q_) + i_;
    int m0 = (wgid / gridDim.x) * 128, n0 = (wgid % gridDim.x) * 128;

    int wm = (w >> 1) * 64, wn = (w & 1) * 64;
    f32x4 acc[4][4] = {};

    int srow[4], scol[4];
#pragma unroll
    for (int c = 0; c < 4; c++) {
        int b = (w * 4 + c) * 1024 + l * 16;
        int row = b >> 7, inner = b & 127;
        srow[c] = row;
        scol[c] = (inner ^ ((row & 7) << 4)) >> 1;
    }
    int nk = K >> 6;
    for (int kt = 0; kt < nk; ++kt) {
        int kb = kt << 6;
#pragma unroll
        for (int c = 0; c < 4; c++) {
            gload16(A + (size_t)(m0 + srow[c]) * K + kb + scol[c], (char*)As + (w * 4 + c) * 1024);
            gload16(Bt + (size_t)(n0 + srow[c]) * K + kb + scol[c], (char*)Bs + (w * 4 + c) * 1024);
        }
        __syncthreads();
#pragma unroll
        for (int kc = 0; kc < 2; ++kc) {
            int co = (kc * 32 + (l >> 4) * 8) * 2;
            u16x8 af[4], bf[4];
#pragma unroll
            for (int mf = 0; mf < 4; ++mf) {
                int row = wm + mf * 16 + (l & 15);
                af[mf] = *(const u16x8*)((const char*)As + row * 128 + (co ^ ((row & 7) << 4)));
            }
#pragma unroll
            for (int nf = 0; nf < 4; ++nf) {
                int row = wn + nf * 16 + (l & 15);
                bf[nf] = *(const u16x8*)((const char*)Bs + row * 128 + (co ^ ((row & 7) << 4)));
            }
#pragma unroll
            for (int mf = 0; mf < 4; ++mf)
#pragma unroll
                for (int nf = 0; nf < 4; ++nf)
                    acc[mf][nf] = mfma_bf16(af[mf], bf[nf], acc[mf][nf]);
        }
        __syncthreads();
    }
#pragma unroll
    for (int mf = 0; mf < 4; ++mf) {
#pragma unroll
        for (int nf = 0; nf < 4; ++nf) {
            int col = n0 + wn + nf * 16 + (l & 15);
            float bv = bias ? bias[col] : 0.0f;
            float scl = (col < qn) ? qscale : 1.0f;   // uniform per 16-lane group
            if (VSPLIT && col >= 1280) {
                // transposed V write: 4 consecutive t at fixed head-dim slot
                int row0 = m0 + wm + mf * 16 + (l >> 4) * 4;
                int b_ = row0 >> 12, t_ = row0 & 4095;
                u16x4 pk;
#pragma unroll
                for (int r = 0; r < 4; r++) pk[r] = f2bf(acc[mf][nf][r] + bv);
                *(u16x4*)(vt + ((size_t)(b_ * 256 + (col - 1280)) << 12) + t_) = pk;
            } else {
#pragma unroll
                for (int r = 0; r < 4; r++) {
                    int row = m0 + wm + mf * 16 + (l >> 4) * 4 + r;
                    float v = (acc[mf][nf][r] + bv) * scl;
                    if (F32OUT) ((float*)Cp)[(size_t)row * N + col] = v;
                    else        ((u16*)Cp)[(size_t)row * N + col] = f2bf(v);
                }
            }
        }
    }
}

// ---------------- banded GQA flash attention (R8 structure, measured 41.7us) ----------------
// Frozen: 5 perturbations (R4/R6/R7/R9/R11) all regressed.

__global__ __launch_bounds__(512, 4) void attn_kernel(
    const u16* __restrict__ qkv, const u16* __restrict__ vt, u16* __restrict__ y) {
    __shared__ __align__(16) u16 Ks[64 * 64];
    __shared__ __align__(16) u16 Vs[64 * 64];
    __shared__ __align__(16) u16 Ps[8][16 * 64];
    int tid = threadIdx.x, l = tid & 63, w = tid >> 6;
    int qb = ((blockIdx.x & 7) << 3) | (blockIdx.x >> 3);
    int h = blockIdx.y >> 1, hp = blockIdx.y & 1, b = blockIdx.z;
    int qstart = qb * 64;
    size_t rowbase = (size_t)b * 4096;
    int hq = h * 4 + hp * 2 + (w >> 2);
    int qrow0 = (w & 3) * 16;

    u16x8 qf_[2];
#pragma unroll
    for (int kc = 0; kc < 2; ++kc)
        qf_[kc] = *(const u16x8*)(qkv + (rowbase + qstart + qrow0 + (l & 15)) * 1536
                                  + hq * 64 + kc * 32 + (l >> 4) * 8);

    f32x4 o[4] = {};
    float mrow = -__builtin_inff(), srow_ = 0.f;

    const u16* kbase_ptr = qkv + 1024 + h * 64;
    const u16* vbase_ptr = vt + (size_t)((b * 4 + h) * 64) * 4096;

    int sb_ = w * 1024 + l * 16;
    int g_row = sb_ >> 7, g_inner = sb_ & 127;
    int g_col = (g_inner ^ ((g_row & 7) << 4)) >> 1;

#pragma unroll
    for (int kstart = qstart - 256; kstart <= qstart + 256; kstart += 64) {
        if (kstart < 0 || kstart >= 4096) continue;
        gload16(kbase_ptr + (rowbase + kstart + g_row) * 1536 + g_col, (char*)Ks + w * 1024);
        gload16(vbase_ptr + (size_t)g_row * 4096 + kstart + g_col, (char*)Vs + w * 1024);
        __syncthreads();

        f32x4 st[4] = {};
#pragma unroll
        for (int kc = 0; kc < 2; ++kc) {
            int co = (kc * 32 + (l >> 4) * 8) * 2;
#pragma unroll
            for (int kf = 0; kf < 4; ++kf) {
                int row = kf * 16 + (l & 15);
                u16x8 kfr = *(const u16x8*)((const char*)Ks + row * 128 + (co ^ ((row & 7) << 4)));
                st[kf] = mfma_bf16(kfr, qf_[kc], st[kf]);
            }
        }

        bool mlo = (kstart == qstart - 256);
        bool mhi = (kstart == qstart + 256);

        int qoff = qrow0 + (l & 15);
        float pmax = -1e30f;
        float sv[4][4];
#pragma unroll
        for (int kf = 0; kf < 4; ++kf)
#pragma unroll
            for (int r = 0; r < 4; r++) {
                int koff = kf * 16 + (l >> 4) * 4 + r;
                float v = st[kf][r];
                if (mlo && koff < qoff) v = -1e30f;
                if (mhi && koff > qoff) v = -1e30f;
                sv[kf][r] = v;
                pmax = fmaxf(pmax, v);
            }
        pmax = fmaxf(pmax, __shfl_xor(pmax, 16));
        pmax = fmaxf(pmax, __shfl_xor(pmax, 32));

        bool resc = !__all(pmax - mrow <= 8.0f);
        float newm = resc ? fmaxf(mrow, pmax) : mrow;
        float psum = 0.f;
#pragma unroll
        for (int kf = 0; kf < 4; ++kf) {
            u16x4 pk;
#pragma unroll
            for (int r = 0; r < 4; r++) {
                float e = __builtin_amdgcn_exp2f(sv[kf][r] - newm);
                psum += e;
                pk[r] = pbf(e);
            }
            int row = l & 15;
            int keyc = kf * 16 + (l >> 4) * 4;
            *(u16x4*)((char*)Ps[w] + ((row * 128 + keyc * 2) ^ ((row & 7) << 4))) = pk;
        }
        psum += __shfl_xor(psum, 16);
        psum += __shfl_xor(psum, 32);
        if (resc) {
            float fs = __builtin_amdgcn_exp2f(mrow - newm);
            srow_ = srow_ * fs + psum;
            mrow = newm;
#pragma unroll
            for (int r = 0; r < 4; r++) {
                float fb = __shfl(fs, (l >> 4) * 4 + r);
#pragma unroll
                for (int nf = 0; nf < 4; ++nf) o[nf][r] *= fb;
            }
        } else {
            srow_ += psum;
        }

#pragma unroll
        for (int kc = 0; kc < 2; ++kc) {
            int co = (kc * 32 + (l >> 4) * 8) * 2;
            int prow = l & 15;
            u16x8 pa = *(const u16x8*)((const char*)Ps[w] + ((prow * 128 + co) ^ ((prow & 7) << 4)));
#pragma unroll
            for (int nf = 0; nf < 4; ++nf) {
                int row = nf * 16 + (l & 15);
                u16x8 vb = *(const u16x8*)((const char*)Vs + row * 128 + (co ^ ((row & 7) << 4)));
                o[nf] = mfma_bf16(pa, vb, o[nf]);
            }
        }
        __syncthreads();
    }

    float inv = 1.0f / srow_;
#pragma unroll
    for (int r = 0; r < 4; r++) {
        float sb = __shfl(inv, (l >> 4) * 4 + r);
        int row = qstart + qrow0 + (l >> 4) * 4 + r;
#pragma unroll
        for (int nf = 0; nf < 4; ++nf) {
            int col = hq * 64 + nf * 16 + (l & 15);
            y[(rowbase + row) * 1024 + col] = f2bf(o[nf][r] * sb);
        }
    }
}

// ---------------- host launch ----------------

extern "C" void kernel_launch(void* const* d_in, const int* in_sizes, int n_in,
                              void* d_out, int out_size, void* d_ws, size_t ws_size,
                              hipStream_t stream) {
    const float* x  = (const float*)d_in[0];
    const float* wq = (const float*)d_in[1];
    const float* bq = (const float*)d_in[2];
    const float* wk = (const float*)d_in[3];
    const float* bk = (const float*)d_in[4];
    const float* wv = (const float*)d_in[5];
    const float* bv = (const float*)d_in[6];
    const float* wo = (const float*)d_in[7];
    const float* bo = (const float*)d_in[8];
    float* out = (float*)d_out;

    char* p = (char*)d_ws;
    u16* xb     = (u16*)p;   p += (size_t)8192 * 1024 * 2;   // x bf16
    u16* wqkvt  = (u16*)p;   p += (size_t)1536 * 1024 * 2;   // [n][k] bf16 (q,k,v concat)
    u16* wot    = (u16*)p;   p += (size_t)1024 * 1024 * 2;   // wo^T bf16
    float* bqkv = (float*)p; p += 8192;                      // 1536 fp32 (padded)
    u16* qkvb   = (u16*)p;   p += (size_t)8192 * 1536 * 2;   // QKV bf16 (V-section unused)
    u16* vtb    = (u16*)p;   p += (size_t)512 * 4096 * 2;    // V^T bf16
    u16* yb     = (u16*)p;                                   // attn out bf16

    prep_kernel<<<8838, 256, 0, stream>>>(x, wq, bq, wk, bk, wv, bv, wo,
                                          xb, wqkvt, wot, bqkv);

    // Q columns pre-scaled by 0.125*log2(e); V n-tiles written transposed to vtb
    gemm_bt<false, true><<<dim3(12, 64), 256, 0, stream>>>(xb, wqkvt, qkvb, bqkv, vtb,
                                                           8192, 1536, 1024, 1024, 0.18033688f);
    attn_kernel<<<dim3(64, 8, 2), 512, 0, stream>>>(qkvb, vtb, yb);
    gemm_bt<true, false><<<dim3(8, 64), 256, 0, stream>>>(yb, wot, out, bo, nullptr,
                                                          8192, 1024, 1024, 0, 1.0f);
}